// Round 1
// baseline (283.500 us; speedup 1.0000x reference)
//
#include <hip/hip_runtime.h>

// B=4, N=64, C=256, H=W=64, ROI=7, S=3, N_INT=21
static constexpr int C_   = 256;
static constexpr int KDIM = 12544;   // C*49
static constexpr float TWO_PI = 6.28318530717958647692f;

// ---------------------------------------------------------------------------
// Kernel 1: per box -> pe_tok (258) in LDS, write base+pos_enc+biases to out,
//           and build bilinear LUTs (x0,x1,wx)/(y0,y1,wy) for the 21-pt grid.
// ---------------------------------------------------------------------------
__global__ __launch_bounds__(256) void k_small(
    const float* __restrict__ boxes,
    const float* __restrict__ cxw, const float* __restrict__ cxb,
    const float* __restrict__ pw,  const float* __restrict__ pb,
    const float* __restrict__ cb,
    float* __restrict__ out,
    float4* __restrict__ lutx, float4* __restrict__ luty)
{
    const int n   = blockIdx.x;
    const int tid = threadIdx.x;

    const float bx1 = boxes[n*4+0], by1 = boxes[n*4+1];
    const float bx2 = boxes[n*4+2], by2 = boxes[n*4+3];
    const float cx = 0.5f*(bx1+bx2), cy = 0.5f*(by1+by2);
    const float wx = bx2-bx1,        wy = by2-by1;

    __shared__ float pe[258];

    if (tid < 128) {
        // pe_tok = [y_enc(128 from cy), x_enc(128 from cx), wy, wx]
        const int   k     = tid & 63;
        const float coord = (tid < 64) ? cy : cx;
        // dim_t[2k] = 10000^(k/64)  -> exp2(k * log2(10000)/64)
        const float d   = exp2f((float)k * (13.287712379549449f / 64.0f));
        const float arg = coord * TWO_PI / d;
        float s, c;
        sincosf(arg, &s, &c);
        const int base = (tid < 64) ? 0 : 128;
        pe[base + 2*k]     = s;   // sin at even slot
        pe[base + 2*k + 1] = c;   // cos at odd slot
    } else if (tid == 128) {
        pe[256] = wy;   // flat[:,3] = h
        pe[257] = wx;   // flat[:,2] = w
    } else if (tid >= 160 && tid < 202) {
        // bilinear LUT for the 21 sample positions along x (and y)
        const int  t   = tid - 160;
        const bool isx = (t < 21);
        const int  i   = isx ? t : (t - 21);
        const float ns = 64.0f / 63.0f;          // W/(W-1)
        const float a1 = (isx ? bx1 : by1) * ns;
        const float a2 = (isx ? bx2 : by2) * ns;
        const float hs = (a2 - a1) * (1.0f / 42.0f);          // /(2*N_INT)
        const float tt = (float)i * (1.0f / 20.0f);           // /(N_INT-1)
        const float g  = a1 + hs + tt * (a2 - a1 - 2.0f*hs);
        float p = g * 63.0f;
        p = fminf(fmaxf(p, 0.0f), 63.0f);
        const float p0 = floorf(p);
        const float w  = p - p0;
        int i0 = (int)p0; i0 = min(i0, 63);
        const int i1 = min(i0 + 1, 63);
        (isx ? lutx : luty)[n*21 + i] = make_float4((float)i0, (float)i1, w, 0.0f);
    }
    __syncthreads();

    // each thread: one output channel o
    const int o = tid;
    float acc = pb[o] + cb[o] + cxb[o];
    acc = fmaf(cxw[o*4+0], cx, acc);
    acc = fmaf(cxw[o*4+1], cy, acc);
    acc = fmaf(cxw[o*4+2], wx, acc);
    acc = fmaf(cxw[o*4+3], wy, acc);
    const float* __restrict__ pwr = pw + o*258;
    for (int k = 0; k < 258; ++k)
        acc = fmaf(pe[k], pwr[k], acc);
    out[n*256 + o] = acc;
}

// ---------------------------------------------------------------------------
// Kernel 2: ROI-align. One thread per (n, c, pooled cell). 9 samples x 4 taps
// using per-box LUTs. Writes A[n][c*49+ij] (the GEMM A matrix) to workspace.
// ---------------------------------------------------------------------------
__global__ __launch_bounds__(256) void k_roi(
    const float* __restrict__ img,
    const float4* __restrict__ lutx, const float4* __restrict__ luty,
    float* __restrict__ A)
{
    const int idx = blockIdx.x * 256 + threadIdx.x;   // exact: 12544*256 items
    const int n   = idx / KDIM;
    const int rem = idx - n * KDIM;
    const int c   = rem / 49;
    const int ij  = rem - c * 49;
    const int pi  = ij / 7;
    const int pj  = ij - pi * 7;
    const int b   = n >> 6;    // N=64 boxes per batch

    const float* __restrict__ imgc = img + (size_t)(((b << 8) + c) << 12); // (b*C+c)*4096

    const float4 lx0 = lutx[n*21 + pj*3 + 0];
    const float4 lx1 = lutx[n*21 + pj*3 + 1];
    const float4 lx2 = lutx[n*21 + pj*3 + 2];

    float acc = 0.0f;
    #pragma unroll
    for (int si = 0; si < 3; ++si) {
        const float4 ly = luty[n*21 + pi*3 + si];
        const float* __restrict__ r0 = imgc + (((int)ly.x) << 6);
        const float* __restrict__ r1 = imgc + (((int)ly.y) << 6);
        const float wyy = ly.z;
        const float4 lxs[3] = {lx0, lx1, lx2};
        #pragma unroll
        for (int sj = 0; sj < 3; ++sj) {
            const float4 lx = lxs[sj];
            const int   x0 = (int)lx.x, x1 = (int)lx.y;
            const float wxx = lx.z;
            const float v00 = r0[x0], v01 = r0[x1];
            const float v10 = r1[x0], v11 = r1[x1];
            const float top = fmaf(v01 - v00, wxx, v00);
            const float bot = fmaf(v11 - v10, wxx, v10);
            acc += fmaf(bot - top, wyy, top);
        }
    }
    A[idx] = acc * (1.0f / 9.0f);
}

// ---------------------------------------------------------------------------
// Kernel 3: fp32 split-K GEMM: out[m][o] += sum_k A[m][k] * W[o][k]
// grid (4,4,16): 64x64 output tile, K-chunk = 16 channels (784).
// LDS staged transposed [49][68] (pad 68 -> 16B aligned float4 rows).
// ---------------------------------------------------------------------------
__global__ __launch_bounds__(256) void k_gemm(
    const float* __restrict__ A, const float* __restrict__ Wm,
    float* __restrict__ out)
{
    __shared__ __align__(16) float As[49][68];
    __shared__ __align__(16) float Bs[49][68];

    const int m0 = blockIdx.x * 64;
    const int o0 = blockIdx.y * 64;
    const int kb = blockIdx.z * 784;
    const int tid = threadIdx.x;
    const int to = (tid & 15) * 4;
    const int tm = (tid >> 4) * 4;

    float acc[4][4] = {};

    for (int kt = 0; kt < 16; ++kt) {
        const int k0 = kb + kt * 49;
        __syncthreads();
        for (int idx = tid; idx < 64*49; idx += 256) {
            const int row = idx / 49;
            const int kk  = idx - row * 49;
            As[kk][row] = A [(m0 + row) * KDIM + k0 + kk];
            Bs[kk][row] = Wm[(o0 + row) * KDIM + k0 + kk];
        }
        __syncthreads();
        #pragma unroll
        for (int k = 0; k < 49; ++k) {
            const float4 a = *(const float4*)&As[k][tm];
            const float4 w = *(const float4*)&Bs[k][to];
            acc[0][0] = fmaf(a.x, w.x, acc[0][0]);
            acc[0][1] = fmaf(a.x, w.y, acc[0][1]);
            acc[0][2] = fmaf(a.x, w.z, acc[0][2]);
            acc[0][3] = fmaf(a.x, w.w, acc[0][3]);
            acc[1][0] = fmaf(a.y, w.x, acc[1][0]);
            acc[1][1] = fmaf(a.y, w.y, acc[1][1]);
            acc[1][2] = fmaf(a.y, w.z, acc[1][2]);
            acc[1][3] = fmaf(a.y, w.w, acc[1][3]);
            acc[2][0] = fmaf(a.z, w.x, acc[2][0]);
            acc[2][1] = fmaf(a.z, w.y, acc[2][1]);
            acc[2][2] = fmaf(a.z, w.z, acc[2][2]);
            acc[2][3] = fmaf(a.z, w.w, acc[2][3]);
            acc[3][0] = fmaf(a.w, w.x, acc[3][0]);
            acc[3][1] = fmaf(a.w, w.y, acc[3][1]);
            acc[3][2] = fmaf(a.w, w.z, acc[3][2]);
            acc[3][3] = fmaf(a.w, w.w, acc[3][3]);
        }
    }

    #pragma unroll
    for (int i = 0; i < 4; ++i)
        #pragma unroll
        for (int j = 0; j < 4; ++j)
            unsafeAtomicAdd(&out[(m0 + tm + i) * 256 + o0 + to + j], acc[i][j]);
}

// ---------------------------------------------------------------------------
extern "C" void kernel_launch(void* const* d_in, const int* in_sizes, int n_in,
                              void* d_out, int out_size, void* d_ws, size_t ws_size,
                              hipStream_t stream)
{
    const float* img   = (const float*)d_in[0];   // (4,256,64,64)
    const float* boxes = (const float*)d_in[1];   // (4,64,2,2)
    const float* convw = (const float*)d_in[2];   // (256,256,7,7)
    const float* convb = (const float*)d_in[3];   // (256,)
    const float* cxw   = (const float*)d_in[4];   // (256,4)
    const float* cxb   = (const float*)d_in[5];   // (256,)
    const float* pw    = (const float*)d_in[6];   // (256,258)
    const float* pb    = (const float*)d_in[7];   // (256,)
    float* out = (float*)d_out;                   // (4,64,256) fp32

    // workspace layout
    float*  A    = (float*)d_ws;                              // 256*12544*4 = 12,845,056 B
    float4* lutx = (float4*)((char*)d_ws + 12845056);         // 256*21*16   =     86,016 B
    float4* luty = (float4*)((char*)d_ws + 12845056 + 86016);

    // 1) base + pos_enc (+ all biases) -> out ; build LUTs
    k_small<<<256, 256, 0, stream>>>(boxes, cxw, cxb, pw, pb, convb, out, lutx, luty);
    // 2) ROI-align -> A
    k_roi<<<12544, 256, 0, stream>>>(img, lutx, luty, A);
    // 3) img_enc GEMM, accumulate into out
    k_gemm<<<dim3(4,4,16), 256, 0, stream>>>(A, convw, out);
}

// Round 5
// 137.443 us; speedup vs baseline: 2.0627x; 2.0627x over previous
//
#include <hip/hip_runtime.h>

// B=4, N=64, C=256, H=W=64, ROI=7, S=3, N_INT=21
static constexpr int KDIM = 12544;   // C*49
static constexpr float TWO_PI = 6.28318530717958647692f;

typedef float f32x4 __attribute__((ext_vector_type(4)));
typedef short bf16x8 __attribute__((ext_vector_type(8)));

__device__ inline float bf2f(unsigned short u) {
    union { unsigned int i; float f; } x; x.i = ((unsigned int)u) << 16; return x.f;
}
__device__ inline unsigned short f2bf(float f) {
    union { float f; unsigned int i; } x; x.f = f;
    unsigned int r = (x.i + 0x7FFFu + ((x.i >> 16) & 1u)) >> 16;
    return (unsigned short)r;
}

// ---------------------------------------------------------------------------
// Kernel 1: per box -> pe_tok (258) in LDS, write base+pos_enc+biases to out,
//           and build bilinear LUTs (x0,x1,wx)/(y0,y1,wy) for the 21-pt grid.
// ---------------------------------------------------------------------------
__global__ __launch_bounds__(256) void k_small(
    const float* __restrict__ boxes,
    const float* __restrict__ cxw, const float* __restrict__ cxb,
    const float* __restrict__ pw,  const float* __restrict__ pb,
    const float* __restrict__ cb,
    float* __restrict__ out,
    float4* __restrict__ lutx, float4* __restrict__ luty)
{
    const int n   = blockIdx.x;
    const int tid = threadIdx.x;

    const float bx1 = boxes[n*4+0], by1 = boxes[n*4+1];
    const float bx2 = boxes[n*4+2], by2 = boxes[n*4+3];
    const float cx = 0.5f*(bx1+bx2), cy = 0.5f*(by1+by2);
    const float wx = bx2-bx1,        wy = by2-by1;

    __shared__ float pe[258];

    if (tid < 128) {
        const int   k     = tid & 63;
        const float coord = (tid < 64) ? cy : cx;
        const float d   = exp2f((float)k * (13.287712379549449f / 64.0f));
        const float arg = coord * TWO_PI / d;
        float s, c;
        sincosf(arg, &s, &c);
        const int base = (tid < 64) ? 0 : 128;
        pe[base + 2*k]     = s;
        pe[base + 2*k + 1] = c;
    } else if (tid == 128) {
        pe[256] = wy;
        pe[257] = wx;
    } else if (tid >= 160 && tid < 202) {
        const int  t   = tid - 160;
        const bool isx = (t < 21);
        const int  i   = isx ? t : (t - 21);
        const float ns = 64.0f / 63.0f;
        const float a1 = (isx ? bx1 : by1) * ns;
        const float a2 = (isx ? bx2 : by2) * ns;
        const float hs = (a2 - a1) * (1.0f / 42.0f);
        const float tt = (float)i * (1.0f / 20.0f);
        const float g  = a1 + hs + tt * (a2 - a1 - 2.0f*hs);
        float p = g * 63.0f;
        p = fminf(fmaxf(p, 0.0f), 63.0f);
        const float p0 = floorf(p);
        const float w  = p - p0;
        int i0 = (int)p0; i0 = min(i0, 63);
        const int i1 = min(i0 + 1, 63);
        (isx ? lutx : luty)[n*21 + i] = make_float4((float)i0, (float)i1, w, 0.0f);
    }
    __syncthreads();

    const int o = tid;
    float acc = pb[o] + cb[o] + cxb[o];
    acc = fmaf(cxw[o*4+0], cx, acc);
    acc = fmaf(cxw[o*4+1], cy, acc);
    acc = fmaf(cxw[o*4+2], wx, acc);
    acc = fmaf(cxw[o*4+3], wy, acc);
    const float* __restrict__ pwr = pw + o*258;
    for (int k = 0; k < 258; ++k)
        acc = fmaf(pe[k], pwr[k], acc);
    out[n*256 + o] = acc;
}

// ---------------------------------------------------------------------------
// Kernel 2: image transpose (b,c,h,w) fp32 -> (b,h,w,c) bf16
// ---------------------------------------------------------------------------
__global__ __launch_bounds__(256) void k_tr(
    const float* __restrict__ img, unsigned short* __restrict__ imgT)
{
    __shared__ float t[64][65];
    const int b  = blockIdx.z;
    const int c0 = blockIdx.x * 64;
    const int p0 = blockIdx.y * 64;         // p = y*64+x
    const int tid = threadIdx.x;
    const int col = tid & 63;
    const int r4  = tid >> 6;
    #pragma unroll
    for (int i = 0; i < 16; ++i) {
        const int row = i*4 + r4;
        t[row][col] = img[((size_t)(b*256 + c0 + row)) * 4096 + p0 + col];
    }
    __syncthreads();
    #pragma unroll
    for (int i = 0; i < 16; ++i) {
        const int prow = i*4 + r4;
        imgT[((size_t)(b*4096 + p0 + prow)) * 256 + c0 + col] = f2bf(t[col][prow]);
    }
}

// ---------------------------------------------------------------------------
// Kernel 3: conv_w (o, c, 49) fp32 -> Wt[o][ij*256+c] bf16 (k-reorder + cast)
// NOTE: launched AFTER k_roi2 — Wt overlays the (then-dead) imgT region.
// ---------------------------------------------------------------------------
__global__ __launch_bounds__(256) void k_wt(
    const float* __restrict__ cw, unsigned short* __restrict__ Wt)
{
    __shared__ float t[12544];
    const int o = blockIdx.x, tid = threadIdx.x;
    #pragma unroll
    for (int i = 0; i < 49; ++i)
        t[i*256 + tid] = cw[(size_t)o*12544 + i*256 + tid];
    __syncthreads();
    for (int ij = 0; ij < 49; ++ij)
        Wt[(size_t)o*12544 + ij*256 + tid] = f2bf(t[tid*49 + ij]);
}

// ---------------------------------------------------------------------------
// Kernel 4: ROI-align, channels-last. 1 wave per (box,cell), lane = 4 channels.
// Every tap is a coalesced 512B wave load. Output A[n][ij*256+c] bf16.
// ---------------------------------------------------------------------------
__global__ __launch_bounds__(256) void k_roi2(
    const unsigned short* __restrict__ imgT,
    const float4* __restrict__ lutx, const float4* __restrict__ luty,
    unsigned short* __restrict__ A)
{
    const int cell = blockIdx.x * 4 + (threadIdx.x >> 6);   // 0..12543
    const int l    = threadIdx.x & 63;
    const int n    = cell / 49;
    const int ij   = cell - n * 49;
    const int pi   = ij / 7;
    const int pj   = ij - pi * 7;
    const int b    = n >> 6;
    const int c4   = l * 4;

    const unsigned short* __restrict__ base = imgT + ((size_t)b << 20) + c4; // b*64*64*256

    const float4 lx0 = lutx[n*21 + pj*3 + 0];
    const float4 lx1 = lutx[n*21 + pj*3 + 1];
    const float4 lx2 = lutx[n*21 + pj*3 + 2];

    float a0 = 0.f, a1 = 0.f, a2 = 0.f, a3 = 0.f;

    #pragma unroll
    for (int si = 0; si < 3; ++si) {
        const float4 ly = luty[n*21 + pi*3 + si];
        const unsigned short* __restrict__ r0 = base + (((int)ly.x) << 14); // y*64*256
        const unsigned short* __restrict__ r1 = base + (((int)ly.y) << 14);
        const float wyy = ly.z;
        const float4 lxs[3] = {lx0, lx1, lx2};
        #pragma unroll
        for (int sj = 0; sj < 3; ++sj) {
            const float4 lx = lxs[sj];
            const int x0 = ((int)lx.x) << 8, x1 = ((int)lx.y) << 8;
            const float wxx = lx.z;
            const ushort4 v00 = *(const ushort4*)(r0 + x0);
            const ushort4 v01 = *(const ushort4*)(r0 + x1);
            const ushort4 v10 = *(const ushort4*)(r1 + x0);
            const ushort4 v11 = *(const ushort4*)(r1 + x1);
            {
                const float t = fmaf(bf2f(v01.x) - bf2f(v00.x), wxx, bf2f(v00.x));
                const float u = fmaf(bf2f(v11.x) - bf2f(v10.x), wxx, bf2f(v10.x));
                a0 += fmaf(u - t, wyy, t);
            }
            {
                const float t = fmaf(bf2f(v01.y) - bf2f(v00.y), wxx, bf2f(v00.y));
                const float u = fmaf(bf2f(v11.y) - bf2f(v10.y), wxx, bf2f(v10.y));
                a1 += fmaf(u - t, wyy, t);
            }
            {
                const float t = fmaf(bf2f(v01.z) - bf2f(v00.z), wxx, bf2f(v00.z));
                const float u = fmaf(bf2f(v11.z) - bf2f(v10.z), wxx, bf2f(v10.z));
                a2 += fmaf(u - t, wyy, t);
            }
            {
                const float t = fmaf(bf2f(v01.w) - bf2f(v00.w), wxx, bf2f(v00.w));
                const float u = fmaf(bf2f(v11.w) - bf2f(v10.w), wxx, bf2f(v10.w));
                a3 += fmaf(u - t, wyy, t);
            }
        }
    }
    const float s = 1.0f / 9.0f;
    ushort4 o4;
    o4.x = f2bf(a0 * s); o4.y = f2bf(a1 * s); o4.z = f2bf(a2 * s); o4.w = f2bf(a3 * s);
    *(ushort4*)(A + (size_t)n*KDIM + ij*256 + c4) = o4;
}

// ---------------------------------------------------------------------------
// Kernel 5: bf16 MFMA split-K GEMM: out[m][o] += sum_k A[m][k]*Wt[o][k]
// grid (4,4,49): 64x64 tile, K-slab 256. LDS XOR-swizzled, 16x16x32 MFMA.
// Swizzle: XOR applied to the FULL linear offset (row*512 + k-bytes) on
// both write and read sides — same involution, no carry, no OOB.
// ---------------------------------------------------------------------------
__global__ __launch_bounds__(256) void k_gemm_mfma(
    const unsigned short* __restrict__ A, const unsigned short* __restrict__ Wt,
    float* __restrict__ out)
{
    __shared__ __align__(16) char lds[65536];   // A: [0,32K), W: [32K,64K)
    const int m0 = blockIdx.x * 64;
    const int o0 = blockIdx.y * 64;
    const int kb = blockIdx.z * 256;            // k elements (bf16)
    const int tid = threadIdx.x;

    // stage A-tile + W-tile (64 rows x 256 k, bf16 = 512B/row) with XOR swizzle
    #pragma unroll
    for (int it = 0; it < 8; ++it) {
        const int chunk = tid + it * 256;       // 0..2047
        const int row = chunk >> 5;             // 32x16B chunks per row
        const int ci  = chunk & 31;
        const int lb  = (row * 512 + ci * 16) ^ ((row & 7) << 4);
        *(float4*)&lds[lb] =
            *(const float4*)(A  + (size_t)(m0 + row) * KDIM + kb + ci * 8);
        *(float4*)&lds[32768 + lb] =
            *(const float4*)(Wt + (size_t)(o0 + row) * KDIM + kb + ci * 8);
    }
    __syncthreads();

    const int w   = tid >> 6;     // wave 0..3 -> output cols w*16..w*16+15
    const int l   = tid & 63;
    const int l15 = l & 15;
    const int lg  = l >> 4;       // k-group 0..3

    f32x4 acc[4] = {};

    const int bcol = w * 16 + l15;
    const int brow512 = bcol * 512;
    const int bxor    = (bcol & 7) << 4;
    #pragma unroll
    for (int ks = 0; ks < 8; ++ks) {
        const int koff = ks * 64 + lg * 16;
        const bf16x8 bfrag = *(const bf16x8*)&lds[32768 + ((brow512 + koff) ^ bxor)];
        #pragma unroll
        for (int mi = 0; mi < 4; ++mi) {
            const int arow = mi * 16 + l15;
            const bf16x8 afrag =
                *(const bf16x8*)&lds[(arow * 512 + koff) ^ ((arow & 7) << 4)];
            acc[mi] = __builtin_amdgcn_mfma_f32_16x16x32_bf16(afrag, bfrag, acc[mi], 0, 0, 0);
        }
    }

    // C/D: col = lane&15, row = (lane>>4)*4 + j   [m89-verified]
    #pragma unroll
    for (int mi = 0; mi < 4; ++mi)
        #pragma unroll
        for (int j = 0; j < 4; ++j) {
            const int m = m0 + mi * 16 + lg * 4 + j;
            const int o = o0 + w * 16 + l15;
            unsafeAtomicAdd(&out[m * 256 + o], acc[mi][j]);
        }
}

// ---------------------------------------------------------------------------
extern "C" void kernel_launch(void* const* d_in, const int* in_sizes, int n_in,
                              void* d_out, int out_size, void* d_ws, size_t ws_size,
                              hipStream_t stream)
{
    const float* img   = (const float*)d_in[0];   // (4,256,64,64)
    const float* boxes = (const float*)d_in[1];   // (4,64,2,2)
    const float* convw = (const float*)d_in[2];   // (256,256,7,7)
    const float* convb = (const float*)d_in[3];   // (256,)
    const float* cxw   = (const float*)d_in[4];   // (256,4)
    const float* cxb   = (const float*)d_in[5];   // (256,)
    const float* pw    = (const float*)d_in[6];   // (256,258)
    const float* pb    = (const float*)d_in[7];   // (256,)
    float* out = (float*)d_out;                   // (4,64,256) fp32

    // workspace layout (bytes) — peak 14,983,168 B
    // [0, 8388608):        imgT (bf16) — dead after k_roi2, then reused for Wt
    // [0, 6422528):        Wt  (bf16)  — written by k_wt AFTER k_roi2
    // [8388608, 14811136): A   (bf16)
    // [14811136, ...):     lutx, luty (float4)
    unsigned short* imgT = (unsigned short*)d_ws;
    unsigned short* Wt   = (unsigned short*)d_ws;
    unsigned short* A    = (unsigned short*)((char*)d_ws + 8388608);
    float4* lutx = (float4*)((char*)d_ws + 14811136);
    float4* luty = (float4*)((char*)d_ws + 14897152);

    k_small<<<256, 256, 0, stream>>>(boxes, cxw, cxb, pw, pb, convb, out, lutx, luty);
    k_tr<<<dim3(4, 64, 4), 256, 0, stream>>>(img, imgT);
    k_roi2<<<3136, 256, 0, stream>>>(imgT, lutx, luty, A);
    k_wt<<<256, 256, 0, stream>>>(convw, Wt);            // overlays imgT (now dead)
    k_gemm_mfma<<<dim3(4, 4, 49), 256, 0, stream>>>(A, Wt, out);
}

// Round 6
// 131.853 us; speedup vs baseline: 2.1501x; 1.0424x over previous
//
#include <hip/hip_runtime.h>

// B=4, N=64, C=256, H=W=64, ROI=7, S=3, N_INT=21
static constexpr int KDIM = 12544;   // C*49
static constexpr float TWO_PI = 6.28318530717958647692f;

typedef float f32x4 __attribute__((ext_vector_type(4)));
typedef short bf16x8 __attribute__((ext_vector_type(8)));

__device__ inline float bf2f(unsigned short u) {
    union { unsigned int i; float f; } x; x.i = ((unsigned int)u) << 16; return x.f;
}
__device__ inline unsigned short f2bf(float f) {
    union { float f; unsigned int i; } x; x.f = f;
    unsigned int r = (x.i + 0x7FFFu + ((x.i >> 16) & 1u)) >> 16;
    return (unsigned short)r;
}

// ---------------------------------------------------------------------------
// Kernel 1: k_prep — three independent jobs fused into one dispatch.
//   blocks [0,256):    per-box pos-enc + base -> out, and bilinear LUTs
//   blocks [256,1280): image transpose (b,c,h,w) fp32 -> (b,h,w,c) bf16
//   blocks [1280,1536): conv_w (o,c,49) -> Wt[o][ij*256+c] bf16
// ---------------------------------------------------------------------------
__global__ __launch_bounds__(256) void k_prep(
    const float* __restrict__ boxes,
    const float* __restrict__ cxw, const float* __restrict__ cxb,
    const float* __restrict__ pw,  const float* __restrict__ pb,
    const float* __restrict__ cb,
    const float* __restrict__ img, const float* __restrict__ convw,
    float* __restrict__ out,
    unsigned short* __restrict__ imgT, unsigned short* __restrict__ Wt,
    float4* __restrict__ lutx, float4* __restrict__ luty)
{
    __shared__ float smem[12544];
    const int bid = blockIdx.x;
    const int tid = threadIdx.x;

    if (bid < 256) {
        // ---- per-box small path ----
        const int n = bid;
        const float bx1 = boxes[n*4+0], by1 = boxes[n*4+1];
        const float bx2 = boxes[n*4+2], by2 = boxes[n*4+3];
        const float cx = 0.5f*(bx1+bx2), cy = 0.5f*(by1+by2);
        const float wx = bx2-bx1,        wy = by2-by1;

        float* pe = smem;   // 258 floats

        if (tid < 128) {
            const int   k     = tid & 63;
            const float coord = (tid < 64) ? cy : cx;
            const float d   = exp2f((float)k * (13.287712379549449f / 64.0f));
            const float arg = coord * TWO_PI / d;
            float s, c;
            sincosf(arg, &s, &c);
            const int base = (tid < 64) ? 0 : 128;
            pe[base + 2*k]     = s;
            pe[base + 2*k + 1] = c;
        } else if (tid == 128) {
            pe[256] = wy;
            pe[257] = wx;
        } else if (tid >= 160 && tid < 202) {
            const int  t   = tid - 160;
            const bool isx = (t < 21);
            const int  i   = isx ? t : (t - 21);
            const float ns = 64.0f / 63.0f;
            const float a1 = (isx ? bx1 : by1) * ns;
            const float a2 = (isx ? bx2 : by2) * ns;
            const float hs = (a2 - a1) * (1.0f / 42.0f);
            const float tt = (float)i * (1.0f / 20.0f);
            const float g  = a1 + hs + tt * (a2 - a1 - 2.0f*hs);
            float p = g * 63.0f;
            p = fminf(fmaxf(p, 0.0f), 63.0f);
            const float p0 = floorf(p);
            const float w  = p - p0;
            int i0 = (int)p0; i0 = min(i0, 63);
            const int i1 = min(i0 + 1, 63);
            (isx ? lutx : luty)[n*21 + i] = make_float4((float)i0, (float)i1, w, 0.0f);
        }
        __syncthreads();

        const int o = tid;
        float acc = pb[o] + cb[o] + cxb[o];
        acc = fmaf(cxw[o*4+0], cx, acc);
        acc = fmaf(cxw[o*4+1], cy, acc);
        acc = fmaf(cxw[o*4+2], wx, acc);
        acc = fmaf(cxw[o*4+3], wy, acc);
        const float* __restrict__ pwr = pw + o*258;
        for (int k = 0; k < 258; ++k)
            acc = fmaf(pe[k], pwr[k], acc);
        out[n*256 + o] = acc;
    } else if (bid < 1280) {
        // ---- transpose path ----
        float (*t)[65] = (float(*)[65])smem;     // 64x65 = 16.6 KB < 50 KB
        const int idx = bid - 256;
        const int b   = idx >> 8;                // 0..3
        const int rem = idx & 255;
        const int c0  = (rem & 3) * 64;
        const int p0  = (rem >> 2) * 64;         // p = y*64+x
        const int col = tid & 63;
        const int r4  = tid >> 6;
        #pragma unroll
        for (int i = 0; i < 16; ++i) {
            const int row = i*4 + r4;
            t[row][col] = img[((size_t)(b*256 + c0 + row)) * 4096 + p0 + col];
        }
        __syncthreads();
        #pragma unroll
        for (int i = 0; i < 16; ++i) {
            const int prow = i*4 + r4;
            imgT[((size_t)(b*4096 + p0 + prow)) * 256 + c0 + col] = f2bf(t[col][prow]);
        }
    } else {
        // ---- conv_w reorder path ----
        const int o = bid - 1280;
        #pragma unroll
        for (int i = 0; i < 49; ++i)
            smem[i*256 + tid] = convw[(size_t)o*12544 + i*256 + tid];
        __syncthreads();
        for (int ij = 0; ij < 49; ++ij)
            Wt[(size_t)o*12544 + ij*256 + tid] = f2bf(smem[tid*49 + ij]);
    }
}

// ---------------------------------------------------------------------------
// Kernel 2: fused ROI + GEMM. grid (8, 49): block = (m-tile of 32 boxes, cell ij).
// Phase R: compute the 32x256 bf16 A-tile for this cell directly into LDS
//          (each wave: 8 boxes, lane = 4 channels, coalesced 512B taps).
// Phase G: stream Wt slab for this cell in 4 chunks of 64 o-rows; 16x16x32 MFMA;
//          write fp32 partial[cell][m][o] (no atomics).
// ---------------------------------------------------------------------------
__global__ __launch_bounds__(256) void k_fused(
    const unsigned short* __restrict__ imgT,
    const unsigned short* __restrict__ Wt,
    const float4* __restrict__ lutx, const float4* __restrict__ luty,
    float* __restrict__ partial)
{
    __shared__ __align__(16) char ldsA[16384];   // 32 rows x 512B, XOR-swizzled
    __shared__ __align__(16) char ldsW[32768];   // 64 rows x 512B, XOR-swizzled

    const int mt = blockIdx.x;          // 0..7
    const int ij = blockIdx.y;          // 0..48
    const int m0 = mt * 32;
    const int pi = ij / 7, pj = ij - pi * 7;
    const int tid = threadIdx.x;
    const int w = tid >> 6, l = tid & 63;
    const int l15 = l & 15, lg = l >> 4;
    const int c4 = l * 4;

    // --- Phase R: ROI A-tile ---
    for (int bi = 0; bi < 8; ++bi) {
        const int r = w * 8 + bi;       // tile row 0..31
        const int n = m0 + r;           // global box 0..255
        const int b = n >> 6;
        const unsigned short* __restrict__ base = imgT + ((size_t)b << 20) + c4;

        const float4 lx0 = lutx[n*21 + pj*3 + 0];
        const float4 lx1 = lutx[n*21 + pj*3 + 1];
        const float4 lx2 = lutx[n*21 + pj*3 + 2];

        float a0 = 0.f, a1 = 0.f, a2 = 0.f, a3 = 0.f;
        #pragma unroll
        for (int si = 0; si < 3; ++si) {
            const float4 ly = luty[n*21 + pi*3 + si];
            const unsigned short* __restrict__ r0 = base + (((int)ly.x) << 14);
            const unsigned short* __restrict__ r1 = base + (((int)ly.y) << 14);
            const float wyy = ly.z;
            const float4 lxs[3] = {lx0, lx1, lx2};
            #pragma unroll
            for (int sj = 0; sj < 3; ++sj) {
                const float4 lx = lxs[sj];
                const int x0 = ((int)lx.x) << 8, x1 = ((int)lx.y) << 8;
                const float wxx = lx.z;
                const ushort4 v00 = *(const ushort4*)(r0 + x0);
                const ushort4 v01 = *(const ushort4*)(r0 + x1);
                const ushort4 v10 = *(const ushort4*)(r1 + x0);
                const ushort4 v11 = *(const ushort4*)(r1 + x1);
                {
                    const float t = fmaf(bf2f(v01.x) - bf2f(v00.x), wxx, bf2f(v00.x));
                    const float u = fmaf(bf2f(v11.x) - bf2f(v10.x), wxx, bf2f(v10.x));
                    a0 += fmaf(u - t, wyy, t);
                }
                {
                    const float t = fmaf(bf2f(v01.y) - bf2f(v00.y), wxx, bf2f(v00.y));
                    const float u = fmaf(bf2f(v11.y) - bf2f(v10.y), wxx, bf2f(v10.y));
                    a1 += fmaf(u - t, wyy, t);
                }
                {
                    const float t = fmaf(bf2f(v01.z) - bf2f(v00.z), wxx, bf2f(v00.z));
                    const float u = fmaf(bf2f(v11.z) - bf2f(v10.z), wxx, bf2f(v10.z));
                    a2 += fmaf(u - t, wyy, t);
                }
                {
                    const float t = fmaf(bf2f(v01.w) - bf2f(v00.w), wxx, bf2f(v00.w));
                    const float u = fmaf(bf2f(v11.w) - bf2f(v10.w), wxx, bf2f(v10.w));
                    a3 += fmaf(u - t, wyy, t);
                }
            }
        }
        const float s = 1.0f / 9.0f;
        ushort4 o4;
        o4.x = f2bf(a0 * s); o4.y = f2bf(a1 * s);
        o4.z = f2bf(a2 * s); o4.w = f2bf(a3 * s);
        // 8B write; XOR swizzle identical to the 16B read side (bits 4..6 only)
        *(ushort4*)&ldsA[(r * 512 + l * 8) ^ ((r & 7) << 4)] = o4;
    }
    __syncthreads();

    // --- Phase G: 4 chunks of 64 output channels ---
    float* __restrict__ pp = partial + (size_t)ij * 65536;
    const int bcol = w * 16 + l15;
    #pragma unroll 1
    for (int oc = 0; oc < 4; ++oc) {
        if (oc) __syncthreads();   // previous chunk's LDS reads complete
        #pragma unroll
        for (int it = 0; it < 8; ++it) {
            const int chunk = tid + it * 256;    // 0..2047
            const int row = chunk >> 5, ci = chunk & 31;
            *(float4*)&ldsW[(row * 512 + ci * 16) ^ ((row & 7) << 4)] =
                *(const float4*)(Wt + (size_t)(oc * 64 + row) * KDIM + ij * 256 + ci * 8);
        }
        __syncthreads();

        f32x4 acc[2] = {};
        #pragma unroll
        for (int ks = 0; ks < 8; ++ks) {
            const int koff = ks * 64 + lg * 16;
            const bf16x8 bfrag =
                *(const bf16x8*)&ldsW[(bcol * 512 + koff) ^ ((bcol & 7) << 4)];
            #pragma unroll
            for (int mi = 0; mi < 2; ++mi) {
                const int arow = mi * 16 + l15;
                const bf16x8 afrag =
                    *(const bf16x8*)&ldsA[(arow * 512 + koff) ^ ((arow & 7) << 4)];
                acc[mi] = __builtin_amdgcn_mfma_f32_16x16x32_bf16(afrag, bfrag, acc[mi], 0, 0, 0);
            }
        }
        // C/D: col = lane&15, row = (lane>>4)*4 + j   [m89-verified]
        #pragma unroll
        for (int mi = 0; mi < 2; ++mi)
            #pragma unroll
            for (int j = 0; j < 4; ++j)
                pp[(m0 + mi * 16 + lg * 4 + j) * 256 + oc * 64 + bcol] = acc[mi][j];
    }
}

// ---------------------------------------------------------------------------
// Kernel 3: deterministic reduction of 49 cell-partials into out.
// ---------------------------------------------------------------------------
__global__ __launch_bounds__(256) void k_reduce(
    const float* __restrict__ partial, float* __restrict__ out)
{
    const int e = blockIdx.x * 256 + threadIdx.x;    // 0..65535
    float s = out[e];
    #pragma unroll
    for (int ij = 0; ij < 49; ++ij)
        s += partial[(size_t)ij * 65536 + e];
    out[e] = s;
}

// ---------------------------------------------------------------------------
extern "C" void kernel_launch(void* const* d_in, const int* in_sizes, int n_in,
                              void* d_out, int out_size, void* d_ws, size_t ws_size,
                              hipStream_t stream)
{
    const float* img   = (const float*)d_in[0];   // (4,256,64,64)
    const float* boxes = (const float*)d_in[1];   // (4,64,2,2)
    const float* convw = (const float*)d_in[2];   // (256,256,7,7)
    const float* convb = (const float*)d_in[3];   // (256,)
    const float* cxw   = (const float*)d_in[4];   // (256,4)
    const float* cxb   = (const float*)d_in[5];   // (256,)
    const float* pw    = (const float*)d_in[6];   // (256,258)
    const float* pb    = (const float*)d_in[7];   // (256,)
    float* out = (float*)d_out;                   // (4,64,256) fp32

    // workspace layout (bytes); ws is 256 MiB (fill counter evidence), no overlays
    unsigned short* imgT    = (unsigned short*)d_ws;                      // [0, 8388608)
    unsigned short* Wt      = (unsigned short*)((char*)d_ws + 8388608);   // [8388608, 14811136)
    float*          partial = (float*)((char*)d_ws + 14811136);          // 49*65536*4 = 12845056
    float4*         lutx    = (float4*)((char*)d_ws + 27656192);         // 86016
    float4*         luty    = (float4*)((char*)d_ws + 27742208);         // 86016

    k_prep<<<1536, 256, 0, stream>>>(boxes, cxw, cxb, pw, pb, convb,
                                     img, convw, out, imgT, Wt, lutx, luty);
    k_fused<<<dim3(8, 49), 256, 0, stream>>>(imgT, Wt, lutx, luty, partial);
    k_reduce<<<256, 256, 0, stream>>>(partial, out);
}

// Round 8
// 128.785 us; speedup vs baseline: 2.2013x; 1.0238x over previous
//
#include <hip/hip_runtime.h>

// B=4, N=64, C=256, H=W=64, ROI=7, S=3, N_INT=21
static constexpr int KDIM = 12544;   // C*49
static constexpr float TWO_PI = 6.28318530717958647692f;

typedef float f32x4 __attribute__((ext_vector_type(4)));
typedef short bf16x8 __attribute__((ext_vector_type(8)));

__device__ inline float bf2f(unsigned short u) {
    union { unsigned int i; float f; } x; x.i = ((unsigned int)u) << 16; return x.f;
}
__device__ inline unsigned short f2bf(float f) {
    union { float f; unsigned int i; } x; x.f = f;
    unsigned int r = (x.i + 0x7FFFu + ((x.i >> 16) & 1u)) >> 16;
    return (unsigned short)r;
}

// ---------------------------------------------------------------------------
// Kernel 1: k_prep — three independent jobs fused into one dispatch.
//   blocks [0,256):    per-box pos-enc + base -> out, and bilinear LUTs
//   blocks [256,1280): image transpose (b,c,h,w) fp32 -> (b,h,w,c) bf16
//   blocks [1280,1536): conv_w (o,c,49) -> Wt[o][ij*256+c] bf16
// ---------------------------------------------------------------------------
__global__ __launch_bounds__(256) void k_prep(
    const float* __restrict__ boxes,
    const float* __restrict__ cxw, const float* __restrict__ cxb,
    const float* __restrict__ pw,  const float* __restrict__ pb,
    const float* __restrict__ cb,
    const float* __restrict__ img, const float* __restrict__ convw,
    float* __restrict__ out,
    unsigned short* __restrict__ imgT, unsigned short* __restrict__ Wt,
    float4* __restrict__ lutx, float4* __restrict__ luty)
{
    __shared__ float smem[12544];
    const int bid = blockIdx.x;
    const int tid = threadIdx.x;

    if (bid < 256) {
        // ---- per-box small path ----
        const int n = bid;
        const float bx1 = boxes[n*4+0], by1 = boxes[n*4+1];
        const float bx2 = boxes[n*4+2], by2 = boxes[n*4+3];
        const float cx = 0.5f*(bx1+bx2), cy = 0.5f*(by1+by2);
        const float wx = bx2-bx1,        wy = by2-by1;

        float* pe = smem;   // 258 floats

        if (tid < 128) {
            const int   k     = tid & 63;
            const float coord = (tid < 64) ? cy : cx;
            const float d   = exp2f((float)k * (13.287712379549449f / 64.0f));
            const float arg = coord * TWO_PI / d;
            float s, c;
            sincosf(arg, &s, &c);
            const int base = (tid < 64) ? 0 : 128;
            pe[base + 2*k]     = s;
            pe[base + 2*k + 1] = c;
        } else if (tid == 128) {
            pe[256] = wy;
            pe[257] = wx;
        } else if (tid >= 160 && tid < 202) {
            const int  t   = tid - 160;
            const bool isx = (t < 21);
            const int  i   = isx ? t : (t - 21);
            const float ns = 64.0f / 63.0f;
            const float a1 = (isx ? bx1 : by1) * ns;
            const float a2 = (isx ? bx2 : by2) * ns;
            const float hs = (a2 - a1) * (1.0f / 42.0f);
            const float tt = (float)i * (1.0f / 20.0f);
            const float g  = a1 + hs + tt * (a2 - a1 - 2.0f*hs);
            float p = g * 63.0f;
            p = fminf(fmaxf(p, 0.0f), 63.0f);
            const float p0 = floorf(p);
            const float w  = p - p0;
            int i0 = (int)p0; i0 = min(i0, 63);
            const int i1 = min(i0 + 1, 63);
            (isx ? lutx : luty)[n*21 + i] = make_float4((float)i0, (float)i1, w, 0.0f);
        }
        __syncthreads();

        const int o = tid;
        float acc = pb[o] + cb[o] + cxb[o];
        acc = fmaf(cxw[o*4+0], cx, acc);
        acc = fmaf(cxw[o*4+1], cy, acc);
        acc = fmaf(cxw[o*4+2], wx, acc);
        acc = fmaf(cxw[o*4+3], wy, acc);
        const float* __restrict__ pwr = pw + o*258;
        for (int k = 0; k < 258; ++k)
            acc = fmaf(pe[k], pwr[k], acc);
        out[n*256 + o] = acc;
    } else if (bid < 1280) {
        // ---- transpose path ----
        float (*t)[65] = (float(*)[65])smem;     // 64x65 floats
        const int idx = bid - 256;
        const int b   = idx >> 8;                // 0..3
        const int rem = idx & 255;
        const int c0  = (rem & 3) * 64;
        const int p0  = (rem >> 2) * 64;         // p = y*64+x
        const int col = tid & 63;
        const int r4  = tid >> 6;
        #pragma unroll
        for (int i = 0; i < 16; ++i) {
            const int row = i*4 + r4;
            t[row][col] = img[((size_t)(b*256 + c0 + row)) * 4096 + p0 + col];
        }
        __syncthreads();
        #pragma unroll
        for (int i = 0; i < 16; ++i) {
            const int prow = i*4 + r4;
            imgT[((size_t)(b*4096 + p0 + prow)) * 256 + c0 + col] = f2bf(t[col][prow]);
        }
    } else {
        // ---- conv_w reorder path ----
        const int o = bid - 1280;
        #pragma unroll
        for (int i = 0; i < 49; ++i)
            smem[i*256 + tid] = convw[(size_t)o*12544 + i*256 + tid];
        __syncthreads();
        for (int ij = 0; ij < 49; ++ij)
            Wt[(size_t)o*12544 + ij*256 + tid] = f2bf(smem[tid*49 + ij]);
    }
}

// ---------------------------------------------------------------------------
// Kernel 2: fused ROI + GEMM. grid (16, 49): block = (m-tile of 16 boxes, cell ij).
// Phase R: compute the 16x256 bf16 A-tile for this cell directly into LDS
//          (each wave: 4 boxes, lane = 4 channels, coalesced 512B taps).
// Phase G: stream Wt slab for this cell in 4 chunks of 64 o-rows; 16x16x32 MFMA;
//          fp32 unsafeAtomicAdd into out (base already written by k_prep).
// LDS = 8K + 32K = 40KB -> 4 blocks/CU.
// ---------------------------------------------------------------------------
__global__ __launch_bounds__(256) void k_fused(
    const unsigned short* __restrict__ imgT,
    const unsigned short* __restrict__ Wt,
    const float4* __restrict__ lutx, const float4* __restrict__ luty,
    float* __restrict__ out)
{
    __shared__ __align__(16) char ldsA[8192];    // 16 rows x 512B, XOR-swizzled
    __shared__ __align__(16) char ldsW[32768];   // 64 rows x 512B, XOR-swizzled

    const int mt = blockIdx.x;          // 0..15
    const int ij = blockIdx.y;          // 0..48
    const int m0 = mt * 16;
    const int pi = ij / 7, pj = ij - pi * 7;
    const int tid = threadIdx.x;
    const int w = tid >> 6, l = tid & 63;
    const int l15 = l & 15, lg = l >> 4;
    const int c4 = l * 4;

    // --- Phase R: ROI A-tile (16 boxes x 256 ch) ---
    for (int bi = 0; bi < 4; ++bi) {
        const int r = w * 4 + bi;       // tile row 0..15
        const int n = m0 + r;           // global box 0..255
        const int b = n >> 6;
        const unsigned short* __restrict__ base = imgT + ((size_t)b << 20) + c4;

        const float4 lx0 = lutx[n*21 + pj*3 + 0];
        const float4 lx1 = lutx[n*21 + pj*3 + 1];
        const float4 lx2 = lutx[n*21 + pj*3 + 2];

        float a0 = 0.f, a1 = 0.f, a2 = 0.f, a3 = 0.f;
        #pragma unroll
        for (int si = 0; si < 3; ++si) {
            const float4 ly = luty[n*21 + pi*3 + si];
            const unsigned short* __restrict__ r0 = base + (((int)ly.x) << 14);
            const unsigned short* __restrict__ r1 = base + (((int)ly.y) << 14);
            const float wyy = ly.z;
            const float4 lxs[3] = {lx0, lx1, lx2};
            #pragma unroll
            for (int sj = 0; sj < 3; ++sj) {
                const float4 lx = lxs[sj];
                const int x0 = ((int)lx.x) << 8, x1 = ((int)lx.y) << 8;
                const float wxx = lx.z;
                const ushort4 v00 = *(const ushort4*)(r0 + x0);
                const ushort4 v01 = *(const ushort4*)(r0 + x1);
                const ushort4 v10 = *(const ushort4*)(r1 + x0);
                const ushort4 v11 = *(const ushort4*)(r1 + x1);
                {
                    const float t = fmaf(bf2f(v01.x) - bf2f(v00.x), wxx, bf2f(v00.x));
                    const float u = fmaf(bf2f(v11.x) - bf2f(v10.x), wxx, bf2f(v10.x));
                    a0 += fmaf(u - t, wyy, t);
                }
                {
                    const float t = fmaf(bf2f(v01.y) - bf2f(v00.y), wxx, bf2f(v00.y));
                    const float u = fmaf(bf2f(v11.y) - bf2f(v10.y), wxx, bf2f(v10.y));
                    a1 += fmaf(u - t, wyy, t);
                }
                {
                    const float t = fmaf(bf2f(v01.z) - bf2f(v00.z), wxx, bf2f(v00.z));
                    const float u = fmaf(bf2f(v11.z) - bf2f(v10.z), wxx, bf2f(v10.z));
                    a2 += fmaf(u - t, wyy, t);
                }
                {
                    const float t = fmaf(bf2f(v01.w) - bf2f(v00.w), wxx, bf2f(v00.w));
                    const float u = fmaf(bf2f(v11.w) - bf2f(v10.w), wxx, bf2f(v10.w));
                    a3 += fmaf(u - t, wyy, t);
                }
            }
        }
        const float s = 1.0f / 9.0f;
        ushort4 o4;
        o4.x = f2bf(a0 * s); o4.y = f2bf(a1 * s);
        o4.z = f2bf(a2 * s); o4.w = f2bf(a3 * s);
        // 8B write; XOR swizzle (bits 4..6) matches the 16B read side
        *(ushort4*)&ldsA[(r * 512 + l * 8) ^ ((r & 7) << 4)] = o4;
    }
    __syncthreads();

    // --- Phase G: 4 chunks of 64 output channels ---
    const int bcol = w * 16 + l15;
    #pragma unroll 1
    for (int oc = 0; oc < 4; ++oc) {
        if (oc) __syncthreads();   // previous chunk's LDS reads complete
        #pragma unroll
        for (int it = 0; it < 8; ++it) {
            const int chunk = tid + it * 256;    // 0..2047
            const int row = chunk >> 5, ci = chunk & 31;
            *(float4*)&ldsW[(row * 512 + ci * 16) ^ ((row & 7) << 4)] =
                *(const float4*)(Wt + (size_t)(oc * 64 + row) * KDIM + ij * 256 + ci * 8);
        }
        __syncthreads();

        f32x4 acc = {};
        #pragma unroll
        for (int ks = 0; ks < 8; ++ks) {
            const int koff = ks * 64 + lg * 16;
            const bf16x8 bfrag =
                *(const bf16x8*)&ldsW[(bcol * 512 + koff) ^ ((bcol & 7) << 4)];
            const bf16x8 afrag =
                *(const bf16x8*)&ldsA[(l15 * 512 + koff) ^ ((l15 & 7) << 4)];
            acc = __builtin_amdgcn_mfma_f32_16x16x32_bf16(afrag, bfrag, acc, 0, 0, 0);
        }
        // C/D: col = lane&15, row = (lane>>4)*4 + j   [m89-verified]
        #pragma unroll
        for (int j = 0; j < 4; ++j)
            unsafeAtomicAdd(&out[(m0 + lg * 4 + j) * 256 + oc * 64 + bcol], acc[j]);
    }
}

// ---------------------------------------------------------------------------
extern "C" void kernel_launch(void* const* d_in, const int* in_sizes, int n_in,
                              void* d_out, int out_size, void* d_ws, size_t ws_size,
                              hipStream_t stream)
{
    const float* img   = (const float*)d_in[0];   // (4,256,64,64)
    const float* boxes = (const float*)d_in[1];   // (4,64,2,2)
    const float* convw = (const float*)d_in[2];   // (256,256,7,7)
    const float* convb = (const float*)d_in[3];   // (256,)
    const float* cxw   = (const float*)d_in[4];   // (256,4)
    const float* cxb   = (const float*)d_in[5];   // (256,)
    const float* pw    = (const float*)d_in[6];   // (256,258)
    const float* pb    = (const float*)d_in[7];   // (256,)
    float* out = (float*)d_out;                   // (4,64,256) fp32

    // workspace layout (bytes); ws is 256 MiB (fill counter evidence)
    unsigned short* imgT = (unsigned short*)d_ws;                      // [0, 8388608)
    unsigned short* Wt   = (unsigned short*)((char*)d_ws + 8388608);   // [8388608, 14811136)
    float4*         lutx = (float4*)((char*)d_ws + 14811136);          // 86016
    float4*         luty = (float4*)((char*)d_ws + 14897152);          // 86016

    k_prep<<<1536, 256, 0, stream>>>(boxes, cxw, cxb, pw, pb, convb,
                                     img, convw, out, imgT, Wt, lutx, luty);
    k_fused<<<dim3(16, 49), 256, 0, stream>>>(imgT, Wt, lutx, luty, out);
}